// Round 5
// baseline (223.834 us; speedup 1.0000x reference)
//
#include <hip/hip_runtime.h>

// VectorQuantizer forward: N=131072 rows of D=64 vs K=1024 codes.
// Outputs flat fp32: [quantized_st (N*D), loss (1), indices-as-float (N)].
//
// Two-tier exactness scheme (validated, absmax 0):
//  - vq_main: bf16 hi/lo split MFMA approx of g[k] = e2[k] - 2*dot (x2 dropped).
//    Rows with (sec - best) < MARGIN are flagged for exact treatment.
//  - vq_cleanup: flagged rows re-scanned with bit-exact numerics.
//
// Round 5: OCCUPANCY. R0-R4 analysis: true pipe utils are ~5-10% (the derived
// counters sum 4 SIMD pipes), per-wave stall ~6900 cy/tile = serialized L2
// latency, and grid 1024 caps occupancy at 16 waves/CU. Fix: 16 rows/wave
// (rt dimension dropped), 64 rows/block, grid 2048 -> 8 blocks/CU = 32
// waves/CU, __launch_bounds__(256,8) capping VGPR at 64 so all 8 blocks are
// co-resident (raggedness would serialize; block time is K-loop-bound).
// K-loop reverted to validated R0 form: direct global B loads, no barriers.
// KEPT: (-2*w) prepack, e2-folded-into-MFMA-C-init, memset merge, MARGIN 5e-5.

#define NROWS 131072
#define DIM 64
#define KCODES 1024
#define MARGIN 5e-5f
#define LOSS_SCALE (1.25f / ((float)NROWS * (float)DIM))

typedef short bf16x8 __attribute__((ext_vector_type(8)));
typedef float f32x4 __attribute__((ext_vector_type(4)));

__device__ __forceinline__ short f2bf(float f) {
    unsigned u = __float_as_uint(f);
    u += 0x7FFF + ((u >> 16) & 1);   // RNE
    return (short)(u >> 16);
}
__device__ __forceinline__ float bf2f(short h) {
    return __uint_as_float(((unsigned)(unsigned short)h) << 16);
}

// Per code k: e2[k] by sequential fmaf (bit-pattern the cleanup relies on),
// plus bf16 hi/lo split of (-2*w) stored in MFMA B-frag order:
//   short index = ((((t*2+ct)*2+kc)*4+q)*16 + m)*8 + j
//   where k = t*32 + ct*16 + m, d = kc*32 + q*8 + j.
// Thread k==0 also zeroes loss + flag counter (replaces two hipMemsetAsync).
__global__ __launch_bounds__(256) void prep_w(const float* __restrict__ w,
                                              float* __restrict__ e2,
                                              short* __restrict__ w_hi,
                                              short* __restrict__ w_lo,
                                              float* __restrict__ out_loss,
                                              unsigned* __restrict__ flag_cnt) {
    int k = blockIdx.x * blockDim.x + threadIdx.x;
    if (k == 0) { *out_loss = 0.0f; *flag_cnt = 0u; }
    if (k >= KCODES) return;
    const float* wk = w + (size_t)k * DIM;
    float r[DIM];
#pragma unroll
    for (int i = 0; i < DIM / 4; ++i) *(float4*)&r[4 * i] = *(const float4*)(wk + 4 * i);
    float s = 0.f;
#pragma unroll
    for (int d = 0; d < DIM; ++d) s = fmaf(r[d], r[d], s);
    e2[k] = s;

    const int t = k >> 5, ct = (k >> 4) & 1, m = k & 15;
#pragma unroll
    for (int kc = 0; kc < 2; ++kc)
#pragma unroll
        for (int q = 0; q < 4; ++q) {
            bf16x8 hv, lv;
#pragma unroll
            for (int j = 0; j < 8; ++j) {
                float f = -2.0f * r[kc * 32 + q * 8 + j];   // exact scale
                short h = f2bf(f);
                hv[j] = h;
                lv[j] = f2bf(f - bf2f(h));
            }
            size_t fo = ((size_t)(((t * 2 + ct) * 2 + kc) * 4 + q) * 16 + m) * 8;
            *(bf16x8*)(w_hi + fo) = hv;
            *(bf16x8*)(w_lo + fo) = lv;
        }
}

// Block: 4 waves x 16 rows = 64 rows. Grid 2048 -> 8 blocks/CU (VGPR<=64).
// No LDS, no barriers in the K-loop; B-frags read directly from global
// (L2-resident 256KB stream), latency hidden by 8 waves/SIMD.
__global__ __launch_bounds__(256, 8) void vq_main(
        const float* __restrict__ x, const float* __restrict__ w,
        const float* __restrict__ e2,
        const short* __restrict__ w_hi, const short* __restrict__ w_lo,
        float* __restrict__ out_q, float* __restrict__ out_loss,
        float* __restrict__ out_idx,
        unsigned* __restrict__ flag_cnt, unsigned* __restrict__ flag_list) {
    const int tid = threadIdx.x;
    const int lane = tid & 63;
    const int wv = tid >> 6;
    const int m = lane & 15;
    const int q = lane >> 4;
    const int block_row0 = blockIdx.x * 64;
    const int wave_row0 = block_row0 + wv * 16;

    __shared__ int sidx[64];
    __shared__ unsigned char sflg[64];
    __shared__ float red[4];

    // ---- A operand: 2 k-chunks; A[m][k=q*8+j], d = kc*32 + q*8 + j ----
    float xa[2][8];
    {
        const float* xr = x + (size_t)(wave_row0 + m) * DIM + q * 8;
        *(float4*)&xa[0][0] = *(const float4*)(xr);
        *(float4*)&xa[0][4] = *(const float4*)(xr + 4);
        *(float4*)&xa[1][0] = *(const float4*)(xr + 32);
        *(float4*)&xa[1][4] = *(const float4*)(xr + 36);
    }
    bf16x8 ah[2], al[2];
#pragma unroll
    for (int c = 0; c < 2; ++c)
#pragma unroll
        for (int j = 0; j < 8; ++j) {
            float f = xa[c][j];
            short h = f2bf(f);
            ah[c][j] = h;
            al[c][j] = f2bf(f - bf2f(h));
        }

    float best[4], sec[4];
    int bidx[4];
#pragma unroll
    for (int r = 0; r < 4; ++r) {
        best[r] = 3.4e38f;
        sec[r] = 3.4e38f;
        bidx[r] = 0;
    }

    // Per-lane B pointers into frag-ordered arrays; tile stride 2048 shorts.
    const short* ph = w_hi + q * 128 + m * 8;
    const short* pl = w_lo + q * 128 + m * 8;
    const float* pe = e2 + m;

    for (int t = 0; t < KCODES / 32; ++t) {
        bf16x8 bh[2][2], bl[2][2];
#pragma unroll
        for (int ct = 0; ct < 2; ++ct)
#pragma unroll
            for (int kc = 0; kc < 2; ++kc) {
                int off = t * 2048 + (ct * 2 + kc) * 512;
                bh[ct][kc] = *(const bf16x8*)(ph + off);
                bl[ct][kc] = *(const bf16x8*)(pl + off);
            }
        float e2c0 = pe[t * 32];
        float e2c1 = pe[t * 32 + 16];

#pragma unroll
        for (int ct = 0; ct < 2; ++ct) {   // ct ascending: idx ascending
            float ei = ct ? e2c1 : e2c0;
            f32x4 a = {ei, ei, ei, ei};
            a = __builtin_amdgcn_mfma_f32_16x16x32_bf16(al[0], bh[ct][0], a, 0, 0, 0);
            a = __builtin_amdgcn_mfma_f32_16x16x32_bf16(ah[0], bl[ct][0], a, 0, 0, 0);
            a = __builtin_amdgcn_mfma_f32_16x16x32_bf16(ah[0], bh[ct][0], a, 0, 0, 0);
            a = __builtin_amdgcn_mfma_f32_16x16x32_bf16(al[1], bh[ct][1], a, 0, 0, 0);
            a = __builtin_amdgcn_mfma_f32_16x16x32_bf16(ah[1], bl[ct][1], a, 0, 0, 0);
            a = __builtin_amdgcn_mfma_f32_16x16x32_bf16(ah[1], bh[ct][1], a, 0, 0, 0);
            int id = t * 32 + ct * 16 + m;
#pragma unroll
            for (int r = 0; r < 4; ++r) {
                float g = a[r];
                bool c = g < best[r];
                sec[r] = fminf(sec[r], fmaxf(g, best[r]));
                if (c) { best[r] = g; bidx[r] = id; }
            }
        }
    }

    // cross-lane reduce over the 16 m-lanes; tie -> lower idx (numpy rule)
#pragma unroll
    for (int off = 1; off < 16; off <<= 1)
#pragma unroll
        for (int r = 0; r < 4; ++r) {
            float ob = __shfl_xor(best[r], off, 64);
            int oi = __shfl_xor(bidx[r], off, 64);
            float os = __shfl_xor(sec[r], off, 64);
            float mx = fmaxf(best[r], ob);
            sec[r] = fminf(fminf(sec[r], os), mx);
            bool take = (ob < best[r]) ||
                        (ob == best[r] && oi < bidx[r]);
            if (take) { best[r] = ob; bidx[r] = oi; }
        }

    if (m == 0) {
#pragma unroll
        for (int r = 0; r < 4; ++r) {
            int lr = wv * 16 + q * 4 + r;
            sidx[lr] = bidx[r];
            bool fl = (sec[r] - best[r]) < MARGIN;
            sflg[lr] = fl ? 1 : 0;
            if (fl) {
                unsigned p = atomicAdd(flag_cnt, 1u);
                flag_list[p] = (unsigned)(block_row0 + lr);
            }
        }
    }
    __syncthreads();

    // ---- output pass: 64 rows, 4 threads/row ----
    float lsum = 0.f;
    const int rl = tid >> 2, part = tid & 3;
    {
        int lr = rl;
        int grow = block_row0 + lr;
        if (!sflg[lr]) {
            int bi = sidx[lr];
            const float* xs = x + (size_t)grow * DIM + part * 16;
            const float* ws = w + (size_t)bi * DIM + part * 16;
            float* os = out_q + (size_t)grow * DIM + part * 16;
#pragma unroll
            for (int i = 0; i < 4; ++i) {
                float4 xv = *(const float4*)(xs + 4 * i);
                float4 wv4 = *(const float4*)(ws + 4 * i);
                float d0 = wv4.x - xv.x, d1 = wv4.y - xv.y;
                float d2 = wv4.z - xv.z, d3 = wv4.w - xv.w;
                lsum = fmaf(d0, d0, lsum);
                lsum = fmaf(d1, d1, lsum);
                lsum = fmaf(d2, d2, lsum);
                lsum = fmaf(d3, d3, lsum);
                float4 o = {xv.x + d0, xv.y + d1, xv.z + d2, xv.w + d3};
                *(float4*)(os + 4 * i) = o;
            }
            if (part == 0) out_idx[grow] = (float)bi;
        }
    }

    for (int off = 32; off > 0; off >>= 1) lsum += __shfl_down(lsum, off, 64);
    if ((tid & 63) == 0) red[tid >> 6] = lsum;
    __syncthreads();
    if (tid == 0) {
        float s = (red[0] + red[1]) + (red[2] + red[3]);
        atomicAdd(out_loss, s * LOSS_SCALE);
    }
}

// Exact re-scan of flagged rows (bit-exact numerics). b128 LDS reads; the fmaf
// chain stays in ascending-d order -> bit-identical dots.
#define CH 16
__global__ __launch_bounds__(256) void vq_cleanup(
        const float* __restrict__ x, const float* __restrict__ w,
        const float* __restrict__ e2,
        const unsigned* __restrict__ flag_cnt,
        const unsigned* __restrict__ flag_list,
        float* __restrict__ out_q, float* __restrict__ out_loss,
        float* __restrict__ out_idx) {
    __shared__ float xs[CH][68];
    __shared__ float wt[128][68];
    __shared__ float sx2[CH];
    const int tid = threadIdx.x;
    const int rowsub = tid >> 4;    // 0..15
    const int kslot = tid & 15;
    const unsigned cnt = *flag_cnt;

    for (unsigned base = blockIdx.x * CH; base < cnt; base += gridDim.x * CH) {
        const int nrows = (int)min((unsigned)CH, cnt - base);
        __syncthreads();
        {
            int rr = tid >> 4, sg = tid & 15;
            if (rr < nrows) {
                unsigned grow = flag_list[base + rr];
                *(float4*)&xs[rr][sg * 4] =
                    *(const float4*)(x + (size_t)grow * DIM + sg * 4);
            }
        }
        __syncthreads();
        if (tid < nrows) {
            float s = 0.f;
#pragma unroll
            for (int d = 0; d < DIM; ++d) s = fmaf(xs[tid][d], xs[tid][d], s);
            sx2[tid] = s;
        }

        unsigned long long kmin = ~0ULL;
        for (int tile = 0; tile < KCODES / 128; ++tile) {
            __syncthreads();
#pragma unroll
            for (int i = 0; i < 8; ++i) {
                int f = tid + i * 256;
                int code = f >> 4, sg = f & 15;
                *(float4*)&wt[code][sg * 4] =
                    *(const float4*)(w + (size_t)(tile * 128 + code) * DIM + sg * 4);
            }
            __syncthreads();
            if (rowsub < nrows) {
#pragma unroll
                for (int j = 0; j < 8; ++j) {
                    int cl = j * 16 + kslot;
                    int code = tile * 128 + cl;
                    float dot = 0.f;
#pragma unroll
                    for (int d4 = 0; d4 < 16; ++d4) {
                        float4 wv4 = *(const float4*)&wt[cl][d4 * 4];
                        float4 xv4 = *(const float4*)&xs[rowsub][d4 * 4];
                        dot = fmaf(wv4.x, xv4.x, dot);
                        dot = fmaf(wv4.y, xv4.y, dot);
                        dot = fmaf(wv4.z, xv4.z, dot);
                        dot = fmaf(wv4.w, xv4.w, dot);
                    }
                    float dist = (sx2[rowsub] + e2[code]) - 2.0f * dot;
                    unsigned long long key =
                        ((unsigned long long)__float_as_uint(dist) << 32) |
                        (unsigned)code;
                    kmin = kmin < key ? kmin : key;
                }
            }
        }
#pragma unroll
        for (int off = 1; off < 16; off <<= 1) {
            unsigned long long o = __shfl_xor(kmin, off, 64);
            kmin = kmin < o ? kmin : o;
        }
        if (rowsub < nrows) {
            int bi = (int)(unsigned)(kmin & 0xFFFFFFFFu);
            unsigned grow = flag_list[base + rowsub];
            float4 x4 = *(float4*)&xs[rowsub][kslot * 4];
            float4 w4 = *(const float4*)(w + (size_t)bi * DIM + kslot * 4);
            float d0 = w4.x - x4.x, d1 = w4.y - x4.y;
            float d2 = w4.z - x4.z, d3 = w4.w - x4.w;
            float ls = 0.f;
            ls = fmaf(d0, d0, ls);
            ls = fmaf(d1, d1, ls);
            ls = fmaf(d2, d2, ls);
            ls = fmaf(d3, d3, ls);
            float4 o = {x4.x + d0, x4.y + d1, x4.z + d2, x4.w + d3};
            *(float4*)(out_q + (size_t)grow * DIM + kslot * 4) = o;
            if (kslot == 0) out_idx[grow] = (float)bi;
#pragma unroll
            for (int off = 1; off < 16; off <<= 1)
                ls += __shfl_xor(ls, off, 64);
            if (kslot == 0) atomicAdd(out_loss, ls * LOSS_SCALE);
        }
    }
}

extern "C" void kernel_launch(void* const* d_in, const int* in_sizes, int n_in,
                              void* d_out, int out_size, void* d_ws, size_t ws_size,
                              hipStream_t stream) {
    const float* x = (const float*)d_in[0];   // [N, D]
    const float* w = (const float*)d_in[1];   // [K, D]

    float* out_q    = (float*)d_out;
    float* out_loss = (float*)d_out + (size_t)NROWS * DIM;
    float* out_idx  = out_loss + 1;

    // ws: e2 (4KB) | w_hi frag-order (128KB) | w_lo (128KB) | cnt | list (512KB)
    float* e2 = (float*)d_ws;
    short* w_hi = (short*)(e2 + KCODES);
    short* w_lo = w_hi + (size_t)KCODES * DIM;
    unsigned* cnt = (unsigned*)(w_lo + (size_t)KCODES * DIM);
    unsigned* list = cnt + 1;

    prep_w<<<(KCODES + 255) / 256, 256, 0, stream>>>(w, e2, w_hi, w_lo,
                                                     out_loss, cnt);
    vq_main<<<NROWS / 64, 256, 0, stream>>>(x, w, e2, w_hi, w_lo,
                                            out_q, out_loss, out_idx, cnt, list);
    vq_cleanup<<<256, 256, 0, stream>>>(x, w, e2, cnt, list,
                                        out_q, out_loss, out_idx);
}

// Round 6
// 202.646 us; speedup vs baseline: 1.1046x; 1.1046x over previous
//
#include <hip/hip_runtime.h>

// VectorQuantizer forward: N=131072 rows of D=64 vs K=1024 codes.
// Outputs flat fp32: [quantized_st (N*D), loss (1), indices-as-float (N)].
//
// Exactness scheme (round 6):
//  - vq_main: bf16 hi/lo split MFMA of g[k] = e2[k] - 2*dot. Per row, the
//    EXACT global top-4 (value,idx) is computed. Classification by the
//    validated MARGIN=5e-5 window around the best:
//      * 1 in-window              -> fast path (validated: approx argmin exact)
//      * 2-3 in-window, no hazard -> inline exact re-check of candidates only
//        (bit-identical cleanup numerics; true argmin provably in-window)
//      * hazards -> full cleanup: 4th in-window (5th may hide), two in-window
//        candidates from same m-lane (id&15 equal: lane top-2 may hide its
//        3rd), or x2>=120 (window bound needs x2+e2 < 128 for fp32-ulp arg)
//  - vq_cleanup: unchanged full exact re-scan, now only for hazard rows.
// Main K-loop = R0 structure (best measured: direct global B-frag loads, no
// LDS/barriers; R1 dbuf, R4 LDS-stage, R5 occupancy all regressed).
// KEPT: (-2*w) prepack, e2-folded-into-MFMA-C-init, memset merge.

#define NROWS 131072
#define DIM 64
#define KCODES 1024
#define MARGIN 5e-5f
#define X2_GUARD 120.0f
#define LOSS_SCALE (1.25f / ((float)NROWS * (float)DIM))
#define PADID (1 << 20)

typedef short bf16x8 __attribute__((ext_vector_type(8)));
typedef float f32x4 __attribute__((ext_vector_type(4)));

__device__ __forceinline__ short f2bf(float f) {
    unsigned u = __float_as_uint(f);
    u += 0x7FFF + ((u >> 16) & 1);   // RNE
    return (short)(u >> 16);
}
__device__ __forceinline__ float bf2f(short h) {
    return __uint_as_float(((unsigned)(unsigned short)h) << 16);
}

// Per code k: e2[k] by sequential fmaf (bit-pattern the exact paths rely on),
// plus bf16 hi/lo split of (-2*w) stored in MFMA B-frag order:
//   short index = ((((t*2+ct)*2+kc)*4+q)*16 + m)*8 + j
//   where k = t*32 + ct*16 + m, d = kc*32 + q*8 + j.
// Thread k==0 also zeroes loss + flag counter.
__global__ __launch_bounds__(256) void prep_w(const float* __restrict__ w,
                                              float* __restrict__ e2,
                                              short* __restrict__ w_hi,
                                              short* __restrict__ w_lo,
                                              float* __restrict__ out_loss,
                                              unsigned* __restrict__ flag_cnt) {
    int k = blockIdx.x * blockDim.x + threadIdx.x;
    if (k == 0) { *out_loss = 0.0f; *flag_cnt = 0u; }
    if (k >= KCODES) return;
    const float* wk = w + (size_t)k * DIM;
    float r[DIM];
#pragma unroll
    for (int i = 0; i < DIM / 4; ++i) *(float4*)&r[4 * i] = *(const float4*)(wk + 4 * i);
    float s = 0.f;
#pragma unroll
    for (int d = 0; d < DIM; ++d) s = fmaf(r[d], r[d], s);
    e2[k] = s;

    const int t = k >> 5, ct = (k >> 4) & 1, m = k & 15;
#pragma unroll
    for (int kc = 0; kc < 2; ++kc)
#pragma unroll
        for (int q = 0; q < 4; ++q) {
            bf16x8 hv, lv;
#pragma unroll
            for (int j = 0; j < 8; ++j) {
                float f = -2.0f * r[kc * 32 + q * 8 + j];   // exact scale
                short h = f2bf(f);
                hv[j] = h;
                lv[j] = f2bf(f - bf2f(h));
            }
            size_t fo = ((size_t)(((t * 2 + ct) * 2 + kc) * 4 + q) * 16 + m) * 8;
            *(bf16x8*)(w_hi + fo) = hv;
            *(bf16x8*)(w_lo + fo) = lv;
        }
}

// compare-exchange / min-pair under (value, idx) lexicographic order
#define MINPAIR(av, ai, bv, bi)                                   \
    { bool tk_ = (bv < av) || (bv == av && bi < ai);              \
      av = tk_ ? bv : av; ai = tk_ ? bi : ai; }
#define CEX(xv, xi, yv, yi)                                       \
    { bool tk_ = (yv < xv) || (yv == xv && yi < xi);              \
      float tv_ = xv; int ti_ = xi;                               \
      xv = tk_ ? yv : xv; xi = tk_ ? yi : xi;                     \
      yv = tk_ ? tv_ : yv; yi = tk_ ? ti_ : yi; }

// Block: 4 waves x 32 rows = 128 rows (R0 structure). No LDS/barriers in the
// K-loop; B-frags are direct global b128 loads from the frag-ordered arrays.
__global__ __launch_bounds__(256, 3) void vq_main(
        const float* __restrict__ x, const float* __restrict__ w,
        const float* __restrict__ e2,
        const short* __restrict__ w_hi, const short* __restrict__ w_lo,
        float* __restrict__ out_q, float* __restrict__ out_loss,
        float* __restrict__ out_idx,
        unsigned* __restrict__ flag_cnt, unsigned* __restrict__ flag_list) {
    const int tid = threadIdx.x;
    const int lane = tid & 63;
    const int wv = tid >> 6;
    const int m = lane & 15;
    const int q = lane >> 4;
    const int block_row0 = blockIdx.x * 128;
    const int wave_row0 = block_row0 + wv * 32;

    __shared__ int sidx[128];
    __shared__ int scnd[128][2];
    __shared__ unsigned char sflg[128];   // 0 fast, 1 two-cand, 2 three-cand, 3 full
    __shared__ float red[4];

    // ---- A operand: 2 rowtiles x 2 k-chunks; A[m][k=q*8+j] ----
    float xa[2][2][8];
#pragma unroll
    for (int rt = 0; rt < 2; ++rt) {
        const float* xr = x + (size_t)(wave_row0 + rt * 16 + m) * DIM + q * 8;
        *(float4*)&xa[rt][0][0] = *(const float4*)(xr);
        *(float4*)&xa[rt][0][4] = *(const float4*)(xr + 4);
        *(float4*)&xa[rt][1][0] = *(const float4*)(xr + 32);
        *(float4*)&xa[rt][1][4] = *(const float4*)(xr + 36);
    }
    bf16x8 ah[2][2], al[2][2];
#pragma unroll
    for (int rt = 0; rt < 2; ++rt)
#pragma unroll
        for (int c = 0; c < 2; ++c)
#pragma unroll
            for (int j = 0; j < 8; ++j) {
                float f = xa[rt][c][j];
                short h = f2bf(f);
                ah[rt][c][j] = h;
                al[rt][c][j] = f2bf(f - bf2f(h));
            }

    float best[2][4], sec[2][4];
    int bidx[2][4], sbix[2][4];
#pragma unroll
    for (int rt = 0; rt < 2; ++rt)
#pragma unroll
        for (int r = 0; r < 4; ++r) {
            best[rt][r] = 3.4e38f;
            sec[rt][r] = 3.4e38f;
            bidx[rt][r] = PADID;
            sbix[rt][r] = PADID;
        }

    // Per-lane B pointers into frag-ordered arrays; tile stride 2048 shorts.
    const short* ph = w_hi + q * 128 + m * 8;
    const short* pl = w_lo + q * 128 + m * 8;
    const float* pe = e2 + m;

    for (int t = 0; t < KCODES / 32; ++t) {
        bf16x8 bh[2][2], bl[2][2];
#pragma unroll
        for (int ct = 0; ct < 2; ++ct)
#pragma unroll
            for (int kc = 0; kc < 2; ++kc) {
                int off = t * 2048 + (ct * 2 + kc) * 512;
                bh[ct][kc] = *(const bf16x8*)(ph + off);
                bl[ct][kc] = *(const bf16x8*)(pl + off);
            }
        float e2c0 = pe[t * 32];
        float e2c1 = pe[t * 32 + 16];

#pragma unroll
        for (int rt = 0; rt < 2; ++rt)
#pragma unroll
            for (int ct = 0; ct < 2; ++ct) {   // ct ascending: idx ascending
                float ei = ct ? e2c1 : e2c0;
                f32x4 a = {ei, ei, ei, ei};
                a = __builtin_amdgcn_mfma_f32_16x16x32_bf16(al[rt][0], bh[ct][0], a, 0, 0, 0);
                a = __builtin_amdgcn_mfma_f32_16x16x32_bf16(ah[rt][0], bl[ct][0], a, 0, 0, 0);
                a = __builtin_amdgcn_mfma_f32_16x16x32_bf16(ah[rt][0], bh[ct][0], a, 0, 0, 0);
                a = __builtin_amdgcn_mfma_f32_16x16x32_bf16(al[rt][1], bh[ct][1], a, 0, 0, 0);
                a = __builtin_amdgcn_mfma_f32_16x16x32_bf16(ah[rt][1], bl[ct][1], a, 0, 0, 0);
                a = __builtin_amdgcn_mfma_f32_16x16x32_bf16(ah[rt][1], bh[ct][1], a, 0, 0, 0);
                int id = t * 32 + ct * 16 + m;
#pragma unroll
                for (int r = 0; r < 4; ++r) {
                    float g = a[r];
                    bool ltb = g < best[rt][r];
                    bool lts = g < sec[rt][r];
                    float nsec = ltb ? best[rt][r] : (lts ? g : sec[rt][r]);
                    int nsid = ltb ? bidx[rt][r] : (lts ? id : sbix[rt][r]);
                    best[rt][r] = ltb ? g : best[rt][r];
                    bidx[rt][r] = ltb ? id : bidx[rt][r];
                    sec[rt][r] = nsec;
                    sbix[rt][r] = nsid;
                }
            }
    }

    // ---- exact global top-4 per row via bitonic 4+4->4 merges over m-lanes ----
    if (m == 0) { /* placeholder to keep structure clear */ }
#pragma unroll
    for (int rt = 0; rt < 2; ++rt)
#pragma unroll
        for (int r = 0; r < 4; ++r) {
            float v0 = best[rt][r], v1 = sec[rt][r], v2 = 3.4e38f, v3 = 3.4e38f;
            int j0 = bidx[rt][r], j1 = sbix[rt][r], j2 = PADID, j3 = PADID;
#pragma unroll
            for (int off = 1; off < 16; off <<= 1) {
                float b0 = __shfl_xor(v0, off, 64);
                float b1 = __shfl_xor(v1, off, 64);
                float b2 = __shfl_xor(v2, off, 64);
                float b3 = __shfl_xor(v3, off, 64);
                int k0 = __shfl_xor(j0, off, 64);
                int k1 = __shfl_xor(j1, off, 64);
                int k2 = __shfl_xor(j2, off, 64);
                int k3 = __shfl_xor(j3, off, 64);
                // bitonic split: lows = min(a_i, b_{3-i}) == 4 smallest of union
                MINPAIR(v0, j0, b3, k3);
                MINPAIR(v1, j1, b2, k2);
                MINPAIR(v2, j2, b1, k1);
                MINPAIR(v3, j3, b0, k0);
                // sort the bitonic 4-list
                CEX(v0, j0, v2, j2);
                CEX(v1, j1, v3, j3);
                CEX(v0, j0, v1, j1);
                CEX(v2, j2, v3, j3);
            }
            if (m == 0) {
                bool w1 = v1 < v0 + MARGIN;
                bool w2 = v2 < v0 + MARGIN;
                bool w3 = v3 < v0 + MARGIN;
                bool samem = (w1 && ((j0 & 15) == (j1 & 15))) ||
                             (w2 && (((j0 & 15) == (j2 & 15)) ||
                                     ((j1 & 15) == (j2 & 15))));
                int meta;
                if (w3 || samem) meta = 3;
                else if (w2) meta = 2;
                else if (w1) meta = 1;
                else meta = 0;
                int lr = wv * 32 + rt * 16 + q * 4 + r;
                sidx[lr] = j0;
                scnd[lr][0] = j1;
                scnd[lr][1] = j2;
                sflg[lr] = (unsigned char)meta;
                if (meta == 3) {
                    unsigned p = atomicAdd(flag_cnt, 1u);
                    flag_list[p] = (unsigned)(block_row0 + lr);
                }
            }
        }
    __syncthreads();

    // ---- output pass: 2 x 64 rows, 4 threads/row ----
    float lsum = 0.f;
    const int rl = tid >> 2, part = tid & 3;
#pragma unroll
    for (int p = 0; p < 2; ++p) {
        int lr = p * 64 + rl;
        int grow = block_row0 + lr;
        int meta = sflg[lr];
        if (meta == 0) {
            int bi = sidx[lr];
            const float* xs = x + (size_t)grow * DIM + part * 16;
            const float* ws = w + (size_t)bi * DIM + part * 16;
            float* os = out_q + (size_t)grow * DIM + part * 16;
#pragma unroll
            for (int i = 0; i < 4; ++i) {
                float4 xv = *(const float4*)(xs + 4 * i);
                float4 wv4 = *(const float4*)(ws + 4 * i);
                float d0 = wv4.x - xv.x, d1 = wv4.y - xv.y;
                float d2 = wv4.z - xv.z, d3 = wv4.w - xv.w;
                lsum = fmaf(d0, d0, lsum);
                lsum = fmaf(d1, d1, lsum);
                lsum = fmaf(d2, d2, lsum);
                lsum = fmaf(d3, d3, lsum);
                float4 o = {xv.x + d0, xv.y + d1, xv.z + d2, xv.w + d3};
                *(float4*)(os + 4 * i) = o;
            }
            if (part == 0) out_idx[grow] = (float)bi;
        } else if (meta != 3) {
            // inline exact re-check among 2-3 candidates (cleanup numerics)
            int nc = meta + 1;
            int cand = (part == 0) ? sidx[lr]
                     : (part == 1) ? scnd[lr][0] : scnd[lr][1];
            unsigned long long key = ~0ULL;
            float x2v = 0.f;
            if (part < nc) {
                const float* xr = x + (size_t)grow * DIM;
                const float* wr = w + (size_t)cand * DIM;
                float dot = 0.f;
#pragma unroll
                for (int d4 = 0; d4 < 16; ++d4) {
                    float4 xv = *(const float4*)(xr + 4 * d4);
                    float4 wv4 = *(const float4*)(wr + 4 * d4);
                    x2v = fmaf(xv.x, xv.x, x2v);
                    x2v = fmaf(xv.y, xv.y, x2v);
                    x2v = fmaf(xv.z, xv.z, x2v);
                    x2v = fmaf(xv.w, xv.w, x2v);
                    dot = fmaf(xv.x, wv4.x, dot);
                    dot = fmaf(xv.y, wv4.y, dot);
                    dot = fmaf(xv.z, wv4.z, dot);
                    dot = fmaf(xv.w, wv4.w, dot);
                }
                float dist = (x2v + e2[cand]) - 2.0f * dot;
                key = ((unsigned long long)__float_as_uint(dist) << 32) |
                      (unsigned)cand;
            }
            {
                unsigned long long o1 = __shfl_xor(key, 1, 64);
                key = key < o1 ? key : o1;
                unsigned long long o2 = __shfl_xor(key, 2, 64);
                key = key < o2 ? key : o2;
            }
            float x2b = __shfl(x2v, lane & 60, 64);   // part0's x2 (part0<nc)
            if (x2b >= X2_GUARD) {
                if (part == 0) {
                    unsigned pp = atomicAdd(flag_cnt, 1u);
                    flag_list[pp] = (unsigned)grow;
                }
            } else {
                int bi = (int)(unsigned)(key & 0xFFFFFFFFu);
                const float* xs = x + (size_t)grow * DIM + part * 16;
                const float* ws = w + (size_t)bi * DIM + part * 16;
                float* os = out_q + (size_t)grow * DIM + part * 16;
#pragma unroll
                for (int i = 0; i < 4; ++i) {
                    float4 xv = *(const float4*)(xs + 4 * i);
                    float4 wv4 = *(const float4*)(ws + 4 * i);
                    float d0 = wv4.x - xv.x, d1 = wv4.y - xv.y;
                    float d2 = wv4.z - xv.z, d3 = wv4.w - xv.w;
                    lsum = fmaf(d0, d0, lsum);
                    lsum = fmaf(d1, d1, lsum);
                    lsum = fmaf(d2, d2, lsum);
                    lsum = fmaf(d3, d3, lsum);
                    float4 o = {xv.x + d0, xv.y + d1, xv.z + d2, xv.w + d3};
                    *(float4*)(os + 4 * i) = o;
                }
                if (part == 0) out_idx[grow] = (float)bi;
            }
        }
        // meta == 3: cleanup kernel writes this row (incl. its loss term)
    }

    for (int off = 32; off > 0; off >>= 1) lsum += __shfl_down(lsum, off, 64);
    if ((tid & 63) == 0) red[tid >> 6] = lsum;
    __syncthreads();
    if (tid == 0) {
        float s = (red[0] + red[1]) + (red[2] + red[3]);
        atomicAdd(out_loss, s * LOSS_SCALE);
    }
}

// Exact re-scan of flagged rows (bit-exact numerics). Unchanged; the list is
// now only hazard rows (~a few % of N).
#define CH 16
__global__ __launch_bounds__(256) void vq_cleanup(
        const float* __restrict__ x, const float* __restrict__ w,
        const float* __restrict__ e2,
        const unsigned* __restrict__ flag_cnt,
        const unsigned* __restrict__ flag_list,
        float* __restrict__ out_q, float* __restrict__ out_loss,
        float* __restrict__ out_idx) {
    __shared__ float xs[CH][68];
    __shared__ float wt[128][68];
    __shared__ float sx2[CH];
    const int tid = threadIdx.x;
    const int rowsub = tid >> 4;    // 0..15
    const int kslot = tid & 15;
    const unsigned cnt = *flag_cnt;

    for (unsigned base = blockIdx.x * CH; base < cnt; base += gridDim.x * CH) {
        const int nrows = (int)min((unsigned)CH, cnt - base);
        __syncthreads();
        {
            int rr = tid >> 4, sg = tid & 15;
            if (rr < nrows) {
                unsigned grow = flag_list[base + rr];
                *(float4*)&xs[rr][sg * 4] =
                    *(const float4*)(x + (size_t)grow * DIM + sg * 4);
            }
        }
        __syncthreads();
        if (tid < nrows) {
            float s = 0.f;
#pragma unroll
            for (int d = 0; d < DIM; ++d) s = fmaf(xs[tid][d], xs[tid][d], s);
            sx2[tid] = s;
        }

        unsigned long long kmin = ~0ULL;
        for (int tile = 0; tile < KCODES / 128; ++tile) {
            __syncthreads();
#pragma unroll
            for (int i = 0; i < 8; ++i) {
                int f = tid + i * 256;
                int code = f >> 4, sg = f & 15;
                *(float4*)&wt[code][sg * 4] =
                    *(const float4*)(w + (size_t)(tile * 128 + code) * DIM + sg * 4);
            }
            __syncthreads();
            if (rowsub < nrows) {
#pragma unroll
                for (int j = 0; j < 8; ++j) {
                    int cl = j * 16 + kslot;
                    int code = tile * 128 + cl;
                    float dot = 0.f;
#pragma unroll
                    for (int d4 = 0; d4 < 16; ++d4) {
                        float4 wv4 = *(const float4*)&wt[cl][d4 * 4];
                        float4 xv4 = *(const float4*)&xs[rowsub][d4 * 4];
                        dot = fmaf(wv4.x, xv4.x, dot);
                        dot = fmaf(wv4.y, xv4.y, dot);
                        dot = fmaf(wv4.z, xv4.z, dot);
                        dot = fmaf(wv4.w, xv4.w, dot);
                    }
                    float dist = (sx2[rowsub] + e2[code]) - 2.0f * dot;
                    unsigned long long key =
                        ((unsigned long long)__float_as_uint(dist) << 32) |
                        (unsigned)code;
                    kmin = kmin < key ? kmin : key;
                }
            }
        }
#pragma unroll
        for (int off = 1; off < 16; off <<= 1) {
            unsigned long long o = __shfl_xor(kmin, off, 64);
            kmin = kmin < o ? kmin : o;
        }
        if (rowsub < nrows) {
            int bi = (int)(unsigned)(kmin & 0xFFFFFFFFu);
            unsigned grow = flag_list[base + rowsub];
            float4 x4 = *(float4*)&xs[rowsub][kslot * 4];
            float4 w4 = *(const float4*)(w + (size_t)bi * DIM + kslot * 4);
            float d0 = w4.x - x4.x, d1 = w4.y - x4.y;
            float d2 = w4.z - x4.z, d3 = w4.w - x4.w;
            float ls = 0.f;
            ls = fmaf(d0, d0, ls);
            ls = fmaf(d1, d1, ls);
            ls = fmaf(d2, d2, ls);
            ls = fmaf(d3, d3, ls);
            float4 o = {x4.x + d0, x4.y + d1, x4.z + d2, x4.w + d3};
            *(float4*)(out_q + (size_t)grow * DIM + kslot * 4) = o;
            if (kslot == 0) out_idx[grow] = (float)bi;
#pragma unroll
            for (int off = 1; off < 16; off <<= 1)
                ls += __shfl_xor(ls, off, 64);
            if (kslot == 0) atomicAdd(out_loss, ls * LOSS_SCALE);
        }
    }
}

extern "C" void kernel_launch(void* const* d_in, const int* in_sizes, int n_in,
                              void* d_out, int out_size, void* d_ws, size_t ws_size,
                              hipStream_t stream) {
    const float* x = (const float*)d_in[0];   // [N, D]
    const float* w = (const float*)d_in[1];   // [K, D]

    float* out_q    = (float*)d_out;
    float* out_loss = (float*)d_out + (size_t)NROWS * DIM;
    float* out_idx  = out_loss + 1;

    // ws: e2 (4KB) | w_hi frag-order (128KB) | w_lo (128KB) | cnt | list (512KB)
    float* e2 = (float*)d_ws;
    short* w_hi = (short*)(e2 + KCODES);
    short* w_lo = w_hi + (size_t)KCODES * DIM;
    unsigned* cnt = (unsigned*)(w_lo + (size_t)KCODES * DIM);
    unsigned* list = cnt + 1;

    prep_w<<<(KCODES + 255) / 256, 256, 0, stream>>>(w, e2, w_hi, w_lo,
                                                     out_loss, cnt);
    vq_main<<<NROWS / 128, 256, 0, stream>>>(x, w, e2, w_hi, w_lo,
                                             out_q, out_loss, out_idx, cnt, list);
    vq_cleanup<<<256, 256, 0, stream>>>(x, w, e2, cnt, list,
                                        out_q, out_loss, out_idx);
}